// Round 1
// baseline (1118.960 us; speedup 1.0000x reference)
//
#include <hip/hip_runtime.h>
#include <hip/hip_bf16.h>
#include <cstdint>

#define NN   100000
#define NE   1600000
#define FIN  512
#define FHID 32
#define FOUT 16

typedef float f32x4 __attribute__((ext_vector_type(4)));
typedef short s16x8 __attribute__((ext_vector_type(8)));

__device__ __forceinline__ short f2bf(float f) {
  union { float f; uint32_t u; } v; v.f = f;
  uint32_t r = v.u + 0x7fffu + ((v.u >> 16) & 1u);
  return (short)(r >> 16);
}

// ---------------- degree count (dst only, reference: ones.at[dst].add(1)) ----
__global__ void k_deg(const int* __restrict__ dst, int* __restrict__ deg) {
  int e = blockIdx.x * blockDim.x + threadIdx.x;
  if (e < NE) atomicAdd(&deg[dst[e]], 1);
}

__global__ void k_dinv(const int* __restrict__ deg, float* __restrict__ dinv) {
  int i = blockIdx.x * blockDim.x + threadIdx.x;
  if (i < NN) dinv[i] = rsqrtf(1.0f + (float)deg[i]);
}

// ---------------- GEMM1: H1[N,32] = x[N,512] @ W1[512,32]  (bf16 MFMA) ------
// mfma_f32_16x16x32_bf16: A lane layout row=l&15, k=8*(l>>4)+i (contiguous k);
// B: col=l&15, same k; C/D: col=lane&15, row=4*(lane>>4)+reg  [m89/m92].
__global__ __launch_bounds__(256) void k_gemm1(const float* __restrict__ x,
                                               const float* __restrict__ W1,
                                               float* __restrict__ H1) {
  __shared__ s16x8 Blds[16][2][64];  // [ktile][ntile][lane] = 32KB bf16 frags
  const int tid = threadIdx.x;
  // cooperative arrange of W1 into per-lane MFMA B fragments
  for (int it = 0; it < 64; ++it) {
    int flat = it * 256 + tid;            // 0..16383 (shorts)
    int i  = flat & 7;
    int l  = (flat >> 3) & 63;
    int nt = (flat >> 9) & 1;
    int kt = flat >> 10;
    int k  = kt * 32 + ((l >> 4) << 3) + i;
    int n  = nt * 16 + (l & 15);
    ((short*)Blds)[flat] = f2bf(W1[k * 32 + n]);
  }
  __syncthreads();

  const int lane = tid & 63;
  const int wv   = tid >> 6;
  const int h    = lane >> 4;   // 0..3
  const int m    = lane & 15;   // 0..15
  const int wid  = blockIdx.x * 4 + wv;   // wave-pair id
  if (wid >= 3125) return;                // 6250 row-tiles, 2 per wave
  const int t0 = wid * 2;

  const float* xr0 = x + (size_t)(t0 * 16 + m) * FIN + h * 8;
  const float* xr1 = xr0 + (size_t)16 * FIN;

  f32x4 acc[2][2] = {};   // [row-tile][ntile]
  #pragma unroll
  for (int kt = 0; kt < 16; ++kt) {
    f32x4 a0 = *(const f32x4*)(xr0 + kt * 32);
    f32x4 a1 = *(const f32x4*)(xr0 + kt * 32 + 4);
    f32x4 c0 = *(const f32x4*)(xr1 + kt * 32);
    f32x4 c1 = *(const f32x4*)(xr1 + kt * 32 + 4);
    s16x8 b0 = Blds[kt][0][lane];
    s16x8 b1 = Blds[kt][1][lane];
    s16x8 af, cf;
    af[0]=f2bf(a0[0]); af[1]=f2bf(a0[1]); af[2]=f2bf(a0[2]); af[3]=f2bf(a0[3]);
    af[4]=f2bf(a1[0]); af[5]=f2bf(a1[1]); af[6]=f2bf(a1[2]); af[7]=f2bf(a1[3]);
    cf[0]=f2bf(c0[0]); cf[1]=f2bf(c0[1]); cf[2]=f2bf(c0[2]); cf[3]=f2bf(c0[3]);
    cf[4]=f2bf(c1[0]); cf[5]=f2bf(c1[1]); cf[6]=f2bf(c1[2]); cf[7]=f2bf(c1[3]);
    acc[0][0] = __builtin_amdgcn_mfma_f32_16x16x32_bf16(af, b0, acc[0][0], 0, 0, 0);
    acc[0][1] = __builtin_amdgcn_mfma_f32_16x16x32_bf16(af, b1, acc[0][1], 0, 0, 0);
    acc[1][0] = __builtin_amdgcn_mfma_f32_16x16x32_bf16(cf, b0, acc[1][0], 0, 0, 0);
    acc[1][1] = __builtin_amdgcn_mfma_f32_16x16x32_bf16(cf, b1, acc[1][1], 0, 0, 0);
  }
  #pragma unroll
  for (int rt = 0; rt < 2; ++rt) {
    float* o = H1 + (size_t)((t0 + rt) * 16 + h * 4) * FHID + m;
    #pragma unroll
    for (int r = 0; r < 4; ++r) {
      o[r * FHID]      = acc[rt][0][r];
      o[r * FHID + 16] = acc[rt][1][r];
    }
  }
}

// ---------------- edge scatter: agg1[dst] += H1[src] * dinv[src]*dinv[dst] --
__global__ void k_agg1(const int* __restrict__ src, const int* __restrict__ dst,
                       const float* __restrict__ dinv,
                       const float* __restrict__ H1, float* __restrict__ agg1) {
  int t = blockIdx.x * blockDim.x + threadIdx.x;
  int e = t >> 3;                      // 8 threads per edge, 4 feats each
  if (e >= NE) return;
  int p = t & 7;
  int s = src[e], d = dst[e];
  float c = dinv[s] * dinv[d];
  f32x4 v = *(const f32x4*)(H1 + (size_t)s * FHID + p * 4);
  float* o = agg1 + (size_t)d * FHID + p * 4;
  atomicAdd(o + 0, v[0] * c);
  atomicAdd(o + 1, v[1] * c);
  atomicAdd(o + 2, v[2] * c);
  atomicAdd(o + 3, v[3] * c);
}

// ---------------- self-loop + bias + relu:  h1 = relu(agg1 + H1/deg + b1) ---
__global__ void k_post1(const float* __restrict__ dinv, const float* __restrict__ b1,
                        const float* __restrict__ H1, float* __restrict__ agg1) {
  int t = blockIdx.x * blockDim.x + threadIdx.x;
  if (t >= NN * 8) return;
  int i = t >> 3, p = t & 7;
  float di = dinv[i], sl = di * di;
  f32x4 hv = *(const f32x4*)(H1   + (size_t)i * FHID + p * 4);
  f32x4 av = *(const f32x4*)(agg1 + (size_t)i * FHID + p * 4);
  f32x4 bv = *(const f32x4*)(b1 + p * 4);
  f32x4 r;
  #pragma unroll
  for (int j = 0; j < 4; ++j) r[j] = fmaxf(av[j] + hv[j] * sl + bv[j], 0.0f);
  *(f32x4*)(agg1 + (size_t)i * FHID + p * 4) = r;
}

// ---------------- GEMM2: H2[N,16] = h1[N,32] @ W2[32,16]  (f32 VALU) -------
__global__ __launch_bounds__(256) void k_gemm2(const float* __restrict__ h1,
                                               const float* __restrict__ W2,
                                               float* __restrict__ H2) {
  __shared__ float w[FHID * FOUT];
  for (int i = threadIdx.x; i < FHID * FOUT; i += 256) w[i] = W2[i];
  __syncthreads();
  int r = blockIdx.x * 256 + threadIdx.x;
  if (r >= NN) return;
  float hr[FHID];
  #pragma unroll
  for (int q = 0; q < 8; ++q) {
    f32x4 v = *(const f32x4*)(h1 + (size_t)r * FHID + q * 4);
    hr[q*4+0] = v[0]; hr[q*4+1] = v[1]; hr[q*4+2] = v[2]; hr[q*4+3] = v[3];
  }
  float acc[FOUT] = {};
  #pragma unroll
  for (int k = 0; k < FHID; ++k)
    #pragma unroll
    for (int j = 0; j < FOUT; ++j)
      acc[j] = fmaf(hr[k], w[k * FOUT + j], acc[j]);
  #pragma unroll
  for (int q = 0; q < 4; ++q) {
    f32x4 v = { acc[q*4+0], acc[q*4+1], acc[q*4+2], acc[q*4+3] };
    *(f32x4*)(H2 + (size_t)r * FOUT + q * 4) = v;
  }
}

// ---------------- edge scatter layer 2 --------------------------------------
__global__ void k_agg2(const int* __restrict__ src, const int* __restrict__ dst,
                       const float* __restrict__ dinv,
                       const float* __restrict__ H2, float* __restrict__ agg2) {
  int t = blockIdx.x * blockDim.x + threadIdx.x;
  int e = t >> 2;                      // 4 threads per edge, 4 feats each
  if (e >= NE) return;
  int p = t & 3;
  int s = src[e], d = dst[e];
  float c = dinv[s] * dinv[d];
  f32x4 v = *(const f32x4*)(H2 + (size_t)s * FOUT + p * 4);
  float* o = agg2 + (size_t)d * FOUT + p * 4;
  atomicAdd(o + 0, v[0] * c);
  atomicAdd(o + 1, v[1] * c);
  atomicAdd(o + 2, v[2] * c);
  atomicAdd(o + 3, v[3] * c);
}

// ---------------- self-loop + bias + log_softmax ----------------------------
__global__ void k_post2(const float* __restrict__ dinv, const float* __restrict__ b2,
                        const float* __restrict__ H2, const float* __restrict__ agg2,
                        float* __restrict__ out) {
  int i = blockIdx.x * blockDim.x + threadIdx.x;
  if (i >= NN) return;
  float di = dinv[i], sl = di * di;
  float z[FOUT];
  float mx = -3.0e38f;
  #pragma unroll
  for (int q = 0; q < 4; ++q) {
    f32x4 h = *(const f32x4*)(H2   + (size_t)i * FOUT + q * 4);
    f32x4 a = *(const f32x4*)(agg2 + (size_t)i * FOUT + q * 4);
    f32x4 b = *(const f32x4*)(b2 + q * 4);
    #pragma unroll
    for (int j = 0; j < 4; ++j) {
      z[q*4+j] = a[j] + h[j] * sl + b[j];
      mx = fmaxf(mx, z[q*4+j]);
    }
  }
  float s = 0.0f;
  #pragma unroll
  for (int k = 0; k < FOUT; ++k) s += expf(z[k] - mx);
  float lse = mx + logf(s);
  #pragma unroll
  for (int q = 0; q < 4; ++q) {
    f32x4 v = { z[q*4+0]-lse, z[q*4+1]-lse, z[q*4+2]-lse, z[q*4+3]-lse };
    *(f32x4*)(out + (size_t)i * FOUT + q * 4) = v;
  }
}

extern "C" void kernel_launch(void* const* d_in, const int* in_sizes, int n_in,
                              void* d_out, int out_size, void* d_ws, size_t ws_size,
                              hipStream_t stream) {
  const float* x  = (const float*)d_in[0];
  const float* W1 = (const float*)d_in[1];
  const float* b1 = (const float*)d_in[2];
  const float* W2 = (const float*)d_in[3];
  const float* b2 = (const float*)d_in[4];
  const int*   ei = (const int*)d_in[5];
  const int* srcv = ei;
  const int* dstv = ei + NE;

  char* ws = (char*)d_ws;
  const size_t MB = 1ull << 20;
  int*   deg  = (int*)  (ws + 0);         //  0.4 MB
  float* agg1 = (float*)(ws + 1  * MB);   // 12.8 MB
  float* agg2 = (float*)(ws + 14 * MB);   //  6.4 MB
  float* dinv = (float*)(ws + 21 * MB);   //  0.4 MB
  float* H1   = (float*)(ws + 22 * MB);   // 12.8 MB
  float* H2   = (float*)(ws + 35 * MB);   //  6.4 MB
  float* out  = (float*)d_out;

  // zero deg + agg1 + agg2 in one contiguous memset
  hipMemsetAsync(ws, 0, 14 * MB + (size_t)NN * FOUT * 4, stream);

  k_deg  <<<(NE + 255) / 256, 256, 0, stream>>>(dstv, deg);
  k_dinv <<<(NN + 255) / 256, 256, 0, stream>>>(deg, dinv);
  k_gemm1<<<782, 256, 0, stream>>>(x, W1, H1);
  k_agg1 <<<(NE * 8) / 256, 256, 0, stream>>>(srcv, dstv, dinv, H1, agg1);
  k_post1<<<(NN * 8 + 255) / 256, 256, 0, stream>>>(dinv, b1, H1, agg1);
  k_gemm2<<<(NN + 255) / 256, 256, 0, stream>>>(agg1, W2, H2);
  k_agg2 <<<(NE * 4) / 256, 256, 0, stream>>>(srcv, dstv, dinv, H2, agg2);
  k_post2<<<(NN + 255) / 256, 256, 0, stream>>>(dinv, b2, H2, agg2, out);
}

// Round 2
// 318.019 us; speedup vs baseline: 3.5185x; 3.5185x over previous
//
#include <hip/hip_runtime.h>
#include <hip/hip_bf16.h>
#include <cstdint>

#define NN   100000
#define NE   1600000
#define FIN  512
#define FHID 32
#define FOUT 16
#define NB   ((NN + 255) / 256)   // 391 scan blocks

typedef float f32x4 __attribute__((ext_vector_type(4)));
typedef short s16x8 __attribute__((ext_vector_type(8)));

__device__ __forceinline__ short f2bf(float f) {
  union { float f; uint32_t u; } v; v.f = f;
  uint32_t r = v.u + 0x7fffu + ((v.u >> 16) & 1u);
  return (short)(r >> 16);
}

// ---------------- degree count (dst only) -----------------------------------
__global__ void k_deg(const int* __restrict__ dst, int* __restrict__ deg) {
  int e = blockIdx.x * blockDim.x + threadIdx.x;
  if (e < NE) atomicAdd(&deg[dst[e]], 1);
}

// ---------------- exclusive scan of deg -> rowstart (3 kernels) -------------
__global__ void k_scan_block(const int* __restrict__ deg, int* __restrict__ rs,
                             int* __restrict__ bsum) {
  __shared__ int tmp[256];
  int i = blockIdx.x * 256 + threadIdx.x;
  int v = (i < NN) ? deg[i] : 0;
  tmp[threadIdx.x] = v;
  __syncthreads();
  #pragma unroll
  for (int off = 1; off < 256; off <<= 1) {
    int t = (threadIdx.x >= off) ? tmp[threadIdx.x - off] : 0;
    __syncthreads();
    tmp[threadIdx.x] += t;
    __syncthreads();
  }
  if (i < NN) rs[i] = tmp[threadIdx.x] - v;        // exclusive
  if (threadIdx.x == 255) bsum[blockIdx.x] = tmp[255];
}

__global__ void k_scan_top(int* __restrict__ bsum) {
  __shared__ int tmp[512];
  int v = (threadIdx.x < NB) ? bsum[threadIdx.x] : 0;
  tmp[threadIdx.x] = v;
  __syncthreads();
  #pragma unroll
  for (int off = 1; off < 512; off <<= 1) {
    int t = (threadIdx.x >= off) ? tmp[threadIdx.x - off] : 0;
    __syncthreads();
    tmp[threadIdx.x] += t;
    __syncthreads();
  }
  if (threadIdx.x < NB) bsum[threadIdx.x] = tmp[threadIdx.x] - v;  // exclusive
}

// rs += block offset; cursor = rs; dinv = rsqrt(1+deg)
__global__ void k_scan_add(int* __restrict__ rs, const int* __restrict__ bsum,
                           int* __restrict__ cur, const int* __restrict__ deg,
                           float* __restrict__ dinv) {
  int i = blockIdx.x * 256 + threadIdx.x;
  if (i >= NN) return;
  int r = rs[i] + bsum[blockIdx.x];
  rs[i] = r;
  cur[i] = r;
  dinv[i] = rsqrtf(1.0f + (float)deg[i]);
}

// ---------------- CSR fill ---------------------------------------------------
__global__ void k_fill(const int* __restrict__ src, const int* __restrict__ dst,
                       int* __restrict__ cur, int* __restrict__ csr) {
  int e = blockIdx.x * blockDim.x + threadIdx.x;
  if (e >= NE) return;
  int s = src[e], d = dst[e];
  int pos = atomicAdd(&cur[d], 1);
  csr[pos] = s;
}

// ---------------- GEMM1: Hs1[N,32] = (x[N,512] @ W1) * dinv[row] ------------
__global__ __launch_bounds__(256) void k_gemm1(const float* __restrict__ x,
                                               const float* __restrict__ W1,
                                               const float* __restrict__ dinv,
                                               float* __restrict__ Hs1) {
  __shared__ s16x8 Blds[16][2][64];
  const int tid = threadIdx.x;
  for (int it = 0; it < 64; ++it) {
    int flat = it * 256 + tid;
    int i  = flat & 7;
    int l  = (flat >> 3) & 63;
    int nt = (flat >> 9) & 1;
    int kt = flat >> 10;
    int k  = kt * 32 + ((l >> 4) << 3) + i;
    int n  = nt * 16 + (l & 15);
    ((short*)Blds)[flat] = f2bf(W1[k * 32 + n]);
  }
  __syncthreads();

  const int lane = tid & 63;
  const int wv   = tid >> 6;
  const int h    = lane >> 4;
  const int m    = lane & 15;
  const int wid  = blockIdx.x * 4 + wv;
  if (wid >= 3125) return;
  const int t0 = wid * 2;

  const float* xr0 = x + (size_t)(t0 * 16 + m) * FIN + h * 8;
  const float* xr1 = xr0 + (size_t)16 * FIN;

  f32x4 acc[2][2] = {};
  #pragma unroll
  for (int kt = 0; kt < 16; ++kt) {
    f32x4 a0 = *(const f32x4*)(xr0 + kt * 32);
    f32x4 a1 = *(const f32x4*)(xr0 + kt * 32 + 4);
    f32x4 c0 = *(const f32x4*)(xr1 + kt * 32);
    f32x4 c1 = *(const f32x4*)(xr1 + kt * 32 + 4);
    s16x8 b0 = Blds[kt][0][lane];
    s16x8 b1 = Blds[kt][1][lane];
    s16x8 af, cf;
    af[0]=f2bf(a0[0]); af[1]=f2bf(a0[1]); af[2]=f2bf(a0[2]); af[3]=f2bf(a0[3]);
    af[4]=f2bf(a1[0]); af[5]=f2bf(a1[1]); af[6]=f2bf(a1[2]); af[7]=f2bf(a1[3]);
    cf[0]=f2bf(c0[0]); cf[1]=f2bf(c0[1]); cf[2]=f2bf(c0[2]); cf[3]=f2bf(c0[3]);
    cf[4]=f2bf(c1[0]); cf[5]=f2bf(c1[1]); cf[6]=f2bf(c1[2]); cf[7]=f2bf(c1[3]);
    acc[0][0] = __builtin_amdgcn_mfma_f32_16x16x32_bf16(af, b0, acc[0][0], 0, 0, 0);
    acc[0][1] = __builtin_amdgcn_mfma_f32_16x16x32_bf16(af, b1, acc[0][1], 0, 0, 0);
    acc[1][0] = __builtin_amdgcn_mfma_f32_16x16x32_bf16(cf, b0, acc[1][0], 0, 0, 0);
    acc[1][1] = __builtin_amdgcn_mfma_f32_16x16x32_bf16(cf, b1, acc[1][1], 0, 0, 0);
  }
  #pragma unroll
  for (int rt = 0; rt < 2; ++rt) {
    #pragma unroll
    for (int r = 0; r < 4; ++r) {
      int row = (t0 + rt) * 16 + h * 4 + r;
      float di = dinv[row];
      float* o = Hs1 + (size_t)row * FHID + m;
      o[0]  = acc[rt][0][r] * di;
      o[16] = acc[rt][1][r] * di;
    }
  }
}

// ------ gather layer 1: h1[d] = relu(dinv[d]*(Σ Hs1[src] + Hs1[d]) + b1) ----
__global__ __launch_bounds__(256) void k_gat1(const int* __restrict__ csr,
                                              const int* __restrict__ rs,
                                              const int* __restrict__ deg,
                                              const float* __restrict__ dinv,
                                              const float* __restrict__ b1,
                                              const float* __restrict__ Hs1,
                                              float* __restrict__ h1) {
  int t = blockIdx.x * 256 + threadIdx.x;
  int d = t >> 3;
  if (d >= NN) return;
  int p = t & 7;
  int start = rs[d], n = deg[d];
  f32x4 a0 = *(const f32x4*)(Hs1 + (size_t)d * FHID + p * 4);  // self-loop
  f32x4 a1 = {}, a2 = {}, a3 = {};
  int j = 0;
  for (; j + 4 <= n; j += 4) {
    int s0 = csr[start + j];
    int s1 = csr[start + j + 1];
    int s2 = csr[start + j + 2];
    int s3 = csr[start + j + 3];
    a0 += *(const f32x4*)(Hs1 + (size_t)s0 * FHID + p * 4);
    a1 += *(const f32x4*)(Hs1 + (size_t)s1 * FHID + p * 4);
    a2 += *(const f32x4*)(Hs1 + (size_t)s2 * FHID + p * 4);
    a3 += *(const f32x4*)(Hs1 + (size_t)s3 * FHID + p * 4);
  }
  for (; j < n; ++j)
    a0 += *(const f32x4*)(Hs1 + (size_t)csr[start + j] * FHID + p * 4);
  f32x4 acc = (a0 + a1) + (a2 + a3);
  float dd = dinv[d];
  f32x4 b = *(const f32x4*)(b1 + p * 4);
  f32x4 r;
  #pragma unroll
  for (int q = 0; q < 4; ++q) r[q] = fmaxf(acc[q] * dd + b[q], 0.0f);
  *(f32x4*)(h1 + (size_t)d * FHID + p * 4) = r;
}

// ---------------- GEMM2: Hs2[N,16] = (h1[N,32] @ W2) * dinv[row] ------------
__global__ __launch_bounds__(256) void k_gemm2(const float* __restrict__ h1,
                                               const float* __restrict__ W2,
                                               const float* __restrict__ dinv,
                                               float* __restrict__ Hs2) {
  __shared__ float w[FHID * FOUT];
  for (int i = threadIdx.x; i < FHID * FOUT; i += 256) w[i] = W2[i];
  __syncthreads();
  int r = blockIdx.x * 256 + threadIdx.x;
  if (r >= NN) return;
  float hr[FHID];
  #pragma unroll
  for (int q = 0; q < 8; ++q) {
    f32x4 v = *(const f32x4*)(h1 + (size_t)r * FHID + q * 4);
    hr[q*4+0] = v[0]; hr[q*4+1] = v[1]; hr[q*4+2] = v[2]; hr[q*4+3] = v[3];
  }
  float acc[FOUT] = {};
  #pragma unroll
  for (int k = 0; k < FHID; ++k)
    #pragma unroll
    for (int jj = 0; jj < FOUT; ++jj)
      acc[jj] = fmaf(hr[k], w[k * FOUT + jj], acc[jj]);
  float di = dinv[r];
  #pragma unroll
  for (int q = 0; q < 4; ++q) {
    f32x4 v = { acc[q*4+0]*di, acc[q*4+1]*di, acc[q*4+2]*di, acc[q*4+3]*di };
    *(f32x4*)(Hs2 + (size_t)r * FOUT + q * 4) = v;
  }
}

// ------ gather layer 2 + bias + log_softmax ---------------------------------
__global__ __launch_bounds__(256) void k_gat2(const int* __restrict__ csr,
                                              const int* __restrict__ rs,
                                              const int* __restrict__ deg,
                                              const float* __restrict__ dinv,
                                              const float* __restrict__ b2,
                                              const float* __restrict__ Hs2,
                                              float* __restrict__ out) {
  int t = blockIdx.x * 256 + threadIdx.x;
  int d = t >> 2;
  if (d >= NN) return;
  int p = t & 3;
  int start = rs[d], n = deg[d];
  f32x4 a0 = *(const f32x4*)(Hs2 + (size_t)d * FOUT + p * 4);  // self-loop
  f32x4 a1 = {}, a2 = {}, a3 = {};
  int j = 0;
  for (; j + 4 <= n; j += 4) {
    int s0 = csr[start + j];
    int s1 = csr[start + j + 1];
    int s2 = csr[start + j + 2];
    int s3 = csr[start + j + 3];
    a0 += *(const f32x4*)(Hs2 + (size_t)s0 * FOUT + p * 4);
    a1 += *(const f32x4*)(Hs2 + (size_t)s1 * FOUT + p * 4);
    a2 += *(const f32x4*)(Hs2 + (size_t)s2 * FOUT + p * 4);
    a3 += *(const f32x4*)(Hs2 + (size_t)s3 * FOUT + p * 4);
  }
  for (; j < n; ++j)
    a0 += *(const f32x4*)(Hs2 + (size_t)csr[start + j] * FOUT + p * 4);
  f32x4 acc = (a0 + a1) + (a2 + a3);
  float dd = dinv[d];
  f32x4 b = *(const f32x4*)(b2 + p * 4);
  f32x4 z;
  #pragma unroll
  for (int q = 0; q < 4; ++q) z[q] = acc[q] * dd + b[q];

  float m = fmaxf(fmaxf(z[0], z[1]), fmaxf(z[2], z[3]));
  m = fmaxf(m, __shfl_xor(m, 1));
  m = fmaxf(m, __shfl_xor(m, 2));
  float s = expf(z[0]-m) + expf(z[1]-m) + expf(z[2]-m) + expf(z[3]-m);
  s += __shfl_xor(s, 1);
  s += __shfl_xor(s, 2);
  float lse = m + logf(s);
  f32x4 o = { z[0]-lse, z[1]-lse, z[2]-lse, z[3]-lse };
  *(f32x4*)(out + (size_t)d * FOUT + p * 4) = o;
}

extern "C" void kernel_launch(void* const* d_in, const int* in_sizes, int n_in,
                              void* d_out, int out_size, void* d_ws, size_t ws_size,
                              hipStream_t stream) {
  const float* x  = (const float*)d_in[0];
  const float* W1 = (const float*)d_in[1];
  const float* b1 = (const float*)d_in[2];
  const float* W2 = (const float*)d_in[3];
  const float* b2 = (const float*)d_in[4];
  const int*   ei = (const int*)d_in[5];
  const int* srcv = ei;
  const int* dstv = ei + NE;

  char* ws = (char*)d_ws;
  const size_t MB = 1ull << 20;
  int*   deg  = (int*)  (ws + 0);              // 0.4 MB
  int*   rs   = (int*)  (ws + (size_t)(0.5 * MB));
  int*   cur  = (int*)  (ws + 1 * MB);
  float* dinv = (float*)(ws + (size_t)(1.5 * MB));
  int*   bsum = (int*)  (ws + 2 * MB);         // 391 ints
  int*   csr  = (int*)  (ws + (size_t)(2.5 * MB));  // 6.4 MB
  float* Hs1  = (float*)(ws + 9  * MB);        // 12.8 MB
  float* h1   = (float*)(ws + 22 * MB);        // 12.8 MB
  float* Hs2  = (float*)(ws + 35 * MB);        // 6.4 MB -> ends 41.4 MB
  float* out  = (float*)d_out;

  hipMemsetAsync(deg, 0, (size_t)NN * 4, stream);

  k_deg       <<<(NE + 255) / 256, 256, 0, stream>>>(dstv, deg);
  k_scan_block<<<NB, 256, 0, stream>>>(deg, rs, bsum);
  k_scan_top  <<<1, 512, 0, stream>>>(bsum);
  k_scan_add  <<<NB, 256, 0, stream>>>(rs, bsum, cur, deg, dinv);
  k_fill      <<<(NE + 255) / 256, 256, 0, stream>>>(srcv, dstv, cur, csr);
  k_gemm1     <<<782, 256, 0, stream>>>(x, W1, dinv, Hs1);
  k_gat1      <<<(NN * 8 + 255) / 256, 256, 0, stream>>>(csr, rs, deg, dinv, b1, Hs1, h1);
  k_gemm2     <<<(NN + 255) / 256, 256, 0, stream>>>(h1, W2, dinv, Hs2);
  k_gat2      <<<(NN * 4 + 255) / 256, 256, 0, stream>>>(csr, rs, deg, dinv, b2, Hs2, out);
}

// Round 3
// 182.105 us; speedup vs baseline: 6.1446x; 1.7464x over previous
//
#include <hip/hip_runtime.h>
#include <hip/hip_bf16.h>
#include <cstdint>

#define NN   100000
#define NE   1600000
#define FIN  512
#define FHID 32
#define FOUT 16

#define BSHIFT 9
#define BSIZE  512
#define NBUCK  196                    // ceil(100000/512)
#define EPB    4096                   // edges per chunk block
#define NCHUNK ((NE + EPB - 1) / EPB) // 391

typedef float f32x4 __attribute__((ext_vector_type(4)));
typedef short s16x8 __attribute__((ext_vector_type(8)));
typedef unsigned int u32;

__device__ __forceinline__ short f2bf(float f) {
  union { float f; uint32_t u; } v; v.f = f;
  uint32_t r = v.u + 0x7fffu + ((v.u >> 16) & 1u);
  return (short)(r >> 16);
}

// ---------------- bucket histogram of dst>>9 --------------------------------
__global__ __launch_bounds__(256) void k_hist(const int* __restrict__ dst,
                                              u32* __restrict__ bcount) {
  __shared__ u32 h[NBUCK];
  int tid = threadIdx.x;
  if (tid < NBUCK) h[tid] = 0;
  __syncthreads();
  int base = blockIdx.x * EPB;
  #pragma unroll
  for (int i = 0; i < EPB / 256; ++i) {
    int e = base + i * 256 + tid;
    if (e < NE) atomicAdd(&h[dst[e] >> BSHIFT], 1u);
  }
  __syncthreads();
  if (tid < NBUCK && h[tid]) atomicAdd(&bcount[tid], h[tid]);
}

// ---------------- scan bucket counts -> bucketStart, init cursors -----------
__global__ __launch_bounds__(256) void k_bscan(const u32* __restrict__ bc,
                                               u32* __restrict__ bstart,
                                               u32* __restrict__ bcur) {
  __shared__ u32 tmp[256];
  int tid = threadIdx.x;
  u32 v = (tid < NBUCK) ? bc[tid] : 0;
  tmp[tid] = v;
  __syncthreads();
  #pragma unroll
  for (int off = 1; off < 256; off <<= 1) {
    u32 t = (tid >= off) ? tmp[tid - off] : 0;
    __syncthreads();
    tmp[tid] += t;
    __syncthreads();
  }
  if (tid < NBUCK) { u32 e = tmp[tid] - v; bstart[tid] = e; bcur[tid] = e; }
  if (tid == 255) bstart[NBUCK] = tmp[255];
}

// ---------------- bin edges by bucket, coalesced writes ---------------------
__global__ __launch_bounds__(256) void k_bin(const int* __restrict__ src,
                                             const int* __restrict__ dst,
                                             u32* __restrict__ bcur,
                                             u32* __restrict__ binned) {
  __shared__ u32 cnt[NBUCK];
  __shared__ u32 lofs[NBUCK];
  __shared__ u32 gbase[NBUCK];
  __shared__ u32 tmp[256];
  __shared__ u32 stage[EPB];
  __shared__ unsigned short sb[EPB];
  int tid = threadIdx.x;
  if (tid < NBUCK) cnt[tid] = 0;
  __syncthreads();

  int base = blockIdx.x * EPB;
  u32 vals[EPB / 256];
  u32 ofs[EPB / 256];
  int bks[EPB / 256];
  #pragma unroll
  for (int i = 0; i < EPB / 256; ++i) {
    int e = base + i * 256 + tid;
    bool ok = e < NE;
    int s = 0, d = 0;
    if (ok) { s = src[e]; d = dst[e]; }
    int b = ok ? (d >> BSHIFT) : -1;
    bks[i] = b;
    vals[i] = (u32)s | ((u32)(d & (BSIZE - 1)) << 17);
    ofs[i] = ok ? atomicAdd(&cnt[b], 1u) : 0;
  }
  __syncthreads();

  // exclusive scan of cnt[196] + reserve global ranges
  u32 cv = (tid < NBUCK) ? cnt[tid] : 0;
  tmp[tid] = cv;
  __syncthreads();
  #pragma unroll
  for (int off = 1; off < 256; off <<= 1) {
    u32 t = (tid >= off) ? tmp[tid - off] : 0;
    __syncthreads();
    tmp[tid] += t;
    __syncthreads();
  }
  if (tid < NBUCK) {
    lofs[tid] = tmp[tid] - cv;
    gbase[tid] = cv ? atomicAdd(&bcur[tid], cv) : 0;
  }
  __syncthreads();
  u32 total = tmp[255];
  __syncthreads();

  #pragma unroll
  for (int i = 0; i < EPB / 256; ++i) {
    if (bks[i] >= 0) {
      u32 sl = lofs[bks[i]] + ofs[i];
      stage[sl] = vals[i];
      sb[sl] = (unsigned short)bks[i];
    }
  }
  __syncthreads();

  for (u32 s2 = tid; s2 < total; s2 += 256) {
    int b = sb[s2];
    binned[gbase[b] + (s2 - lofs[b])] = stage[s2];
  }
}

// ------- finalize per bucket: deg/dinv/rs + csr (block-local writes) --------
__global__ __launch_bounds__(256) void k_fin(const u32* __restrict__ binned,
                                             const u32* __restrict__ bstart,
                                             int* __restrict__ deg,
                                             int* __restrict__ rs,
                                             float* __restrict__ dinv,
                                             int* __restrict__ csr) {
  __shared__ u32 degl[BSIZE];
  __shared__ u32 rsl[BSIZE];
  __shared__ u32 tmp[256];
  int tid = threadIdx.x;
  int b = blockIdx.x;
  u32 start = bstart[b];
  u32 n = bstart[b + 1] - start;

  degl[tid] = 0; degl[tid + 256] = 0;
  __syncthreads();
  for (u32 k = tid; k < n; k += 256)
    atomicAdd(&degl[binned[start + k] >> 17], 1u);
  __syncthreads();

  // exclusive scan of degl[512] with 256 threads
  u32 a0 = degl[2 * tid], a1 = degl[2 * tid + 1];
  u32 s = a0 + a1;
  tmp[tid] = s;
  __syncthreads();
  #pragma unroll
  for (int off = 1; off < 256; off <<= 1) {
    u32 t = (tid >= off) ? tmp[tid - off] : 0;
    __syncthreads();
    tmp[tid] += t;
    __syncthreads();
  }
  u32 e = tmp[tid] - s;
  rsl[2 * tid] = e;
  rsl[2 * tid + 1] = e + a0;
  __syncthreads();

  // node outputs
  #pragma unroll
  for (int q = 0; q < 2; ++q) {
    int t = tid + q * 256;
    int g = b * BSIZE + t;
    if (g < NN) {
      deg[g] = (int)degl[t];
      rs[g] = (int)(start + rsl[t]);
      dinv[g] = rsqrtf(1.0f + (float)degl[t]);
    }
  }
  __syncthreads();

  // place srcs: rsl becomes the cursor (local positions)
  for (u32 k = tid; k < n; k += 256) {
    u32 v = binned[start + k];
    u32 pos = atomicAdd(&rsl[v >> 17], 1u);
    csr[start + pos] = (int)(v & 0x1FFFFu);
  }
}

// ---------------- GEMM1: Hs1[N,32] = (x[N,512] @ W1) * dinv[row] ------------
__global__ __launch_bounds__(256) void k_gemm1(const float* __restrict__ x,
                                               const float* __restrict__ W1,
                                               const float* __restrict__ dinv,
                                               float* __restrict__ Hs1) {
  __shared__ s16x8 Blds[16][2][64];
  const int tid = threadIdx.x;
  for (int it = 0; it < 64; ++it) {
    int flat = it * 256 + tid;
    int i  = flat & 7;
    int l  = (flat >> 3) & 63;
    int nt = (flat >> 9) & 1;
    int kt = flat >> 10;
    int k  = kt * 32 + ((l >> 4) << 3) + i;
    int n  = nt * 16 + (l & 15);
    ((short*)Blds)[flat] = f2bf(W1[k * 32 + n]);
  }
  __syncthreads();

  const int lane = tid & 63;
  const int wv   = tid >> 6;
  const int h    = lane >> 4;
  const int m    = lane & 15;
  const int wid  = blockIdx.x * 4 + wv;
  if (wid >= 3125) return;
  const int t0 = wid * 2;

  const float* xr0 = x + (size_t)(t0 * 16 + m) * FIN + h * 8;
  const float* xr1 = xr0 + (size_t)16 * FIN;

  f32x4 acc[2][2] = {};
  #pragma unroll
  for (int kt = 0; kt < 16; ++kt) {
    f32x4 a0 = *(const f32x4*)(xr0 + kt * 32);
    f32x4 a1 = *(const f32x4*)(xr0 + kt * 32 + 4);
    f32x4 c0 = *(const f32x4*)(xr1 + kt * 32);
    f32x4 c1 = *(const f32x4*)(xr1 + kt * 32 + 4);
    s16x8 b0 = Blds[kt][0][lane];
    s16x8 b1 = Blds[kt][1][lane];
    s16x8 af, cf;
    af[0]=f2bf(a0[0]); af[1]=f2bf(a0[1]); af[2]=f2bf(a0[2]); af[3]=f2bf(a0[3]);
    af[4]=f2bf(a1[0]); af[5]=f2bf(a1[1]); af[6]=f2bf(a1[2]); af[7]=f2bf(a1[3]);
    cf[0]=f2bf(c0[0]); cf[1]=f2bf(c0[1]); cf[2]=f2bf(c0[2]); cf[3]=f2bf(c0[3]);
    cf[4]=f2bf(c1[0]); cf[5]=f2bf(c1[1]); cf[6]=f2bf(c1[2]); cf[7]=f2bf(c1[3]);
    acc[0][0] = __builtin_amdgcn_mfma_f32_16x16x32_bf16(af, b0, acc[0][0], 0, 0, 0);
    acc[0][1] = __builtin_amdgcn_mfma_f32_16x16x32_bf16(af, b1, acc[0][1], 0, 0, 0);
    acc[1][0] = __builtin_amdgcn_mfma_f32_16x16x32_bf16(cf, b0, acc[1][0], 0, 0, 0);
    acc[1][1] = __builtin_amdgcn_mfma_f32_16x16x32_bf16(cf, b1, acc[1][1], 0, 0, 0);
  }
  #pragma unroll
  for (int rt = 0; rt < 2; ++rt) {
    #pragma unroll
    for (int r = 0; r < 4; ++r) {
      int row = (t0 + rt) * 16 + h * 4 + r;
      float di = dinv[row];
      float* o = Hs1 + (size_t)row * FHID + m;
      o[0]  = acc[rt][0][r] * di;
      o[16] = acc[rt][1][r] * di;
    }
  }
}

// ------ gather layer 1: h1[d] = relu(dinv[d]*(Σ Hs1[src] + Hs1[d]) + b1) ----
__global__ __launch_bounds__(256) void k_gat1(const int* __restrict__ csr,
                                              const int* __restrict__ rs,
                                              const int* __restrict__ deg,
                                              const float* __restrict__ dinv,
                                              const float* __restrict__ b1,
                                              const float* __restrict__ Hs1,
                                              float* __restrict__ h1) {
  int t = blockIdx.x * 256 + threadIdx.x;
  int d = t >> 3;
  if (d >= NN) return;
  int p = t & 7;
  int start = rs[d], n = deg[d];
  f32x4 a0 = *(const f32x4*)(Hs1 + (size_t)d * FHID + p * 4);  // self-loop
  f32x4 a1 = {}, a2 = {}, a3 = {};
  int j = 0;
  for (; j + 4 <= n; j += 4) {
    int s0 = csr[start + j];
    int s1 = csr[start + j + 1];
    int s2 = csr[start + j + 2];
    int s3 = csr[start + j + 3];
    a0 += *(const f32x4*)(Hs1 + (size_t)s0 * FHID + p * 4);
    a1 += *(const f32x4*)(Hs1 + (size_t)s1 * FHID + p * 4);
    a2 += *(const f32x4*)(Hs1 + (size_t)s2 * FHID + p * 4);
    a3 += *(const f32x4*)(Hs1 + (size_t)s3 * FHID + p * 4);
  }
  for (; j < n; ++j)
    a0 += *(const f32x4*)(Hs1 + (size_t)csr[start + j] * FHID + p * 4);
  f32x4 acc = (a0 + a1) + (a2 + a3);
  float dd = dinv[d];
  f32x4 b = *(const f32x4*)(b1 + p * 4);
  f32x4 r;
  #pragma unroll
  for (int q = 0; q < 4; ++q) r[q] = fmaxf(acc[q] * dd + b[q], 0.0f);
  *(f32x4*)(h1 + (size_t)d * FHID + p * 4) = r;
}

// ---------------- GEMM2: Hs2[N,16] = (h1[N,32] @ W2) * dinv[row] ------------
__global__ __launch_bounds__(256) void k_gemm2(const float* __restrict__ h1,
                                               const float* __restrict__ W2,
                                               const float* __restrict__ dinv,
                                               float* __restrict__ Hs2) {
  __shared__ float w[FHID * FOUT];
  for (int i = threadIdx.x; i < FHID * FOUT; i += 256) w[i] = W2[i];
  __syncthreads();
  int r = blockIdx.x * 256 + threadIdx.x;
  if (r >= NN) return;
  float hr[FHID];
  #pragma unroll
  for (int q = 0; q < 8; ++q) {
    f32x4 v = *(const f32x4*)(h1 + (size_t)r * FHID + q * 4);
    hr[q*4+0] = v[0]; hr[q*4+1] = v[1]; hr[q*4+2] = v[2]; hr[q*4+3] = v[3];
  }
  float acc[FOUT] = {};
  #pragma unroll
  for (int k = 0; k < FHID; ++k)
    #pragma unroll
    for (int jj = 0; jj < FOUT; ++jj)
      acc[jj] = fmaf(hr[k], w[k * FOUT + jj], acc[jj]);
  float di = dinv[r];
  #pragma unroll
  for (int q = 0; q < 4; ++q) {
    f32x4 v = { acc[q*4+0]*di, acc[q*4+1]*di, acc[q*4+2]*di, acc[q*4+3]*di };
    *(f32x4*)(Hs2 + (size_t)r * FOUT + q * 4) = v;
  }
}

// ------ gather layer 2 + bias + log_softmax ---------------------------------
__global__ __launch_bounds__(256) void k_gat2(const int* __restrict__ csr,
                                              const int* __restrict__ rs,
                                              const int* __restrict__ deg,
                                              const float* __restrict__ dinv,
                                              const float* __restrict__ b2,
                                              const float* __restrict__ Hs2,
                                              float* __restrict__ out) {
  int t = blockIdx.x * 256 + threadIdx.x;
  int d = t >> 2;
  if (d >= NN) return;
  int p = t & 3;
  int start = rs[d], n = deg[d];
  f32x4 a0 = *(const f32x4*)(Hs2 + (size_t)d * FOUT + p * 4);  // self-loop
  f32x4 a1 = {}, a2 = {}, a3 = {};
  int j = 0;
  for (; j + 4 <= n; j += 4) {
    int s0 = csr[start + j];
    int s1 = csr[start + j + 1];
    int s2 = csr[start + j + 2];
    int s3 = csr[start + j + 3];
    a0 += *(const f32x4*)(Hs2 + (size_t)s0 * FOUT + p * 4);
    a1 += *(const f32x4*)(Hs2 + (size_t)s1 * FOUT + p * 4);
    a2 += *(const f32x4*)(Hs2 + (size_t)s2 * FOUT + p * 4);
    a3 += *(const f32x4*)(Hs2 + (size_t)s3 * FOUT + p * 4);
  }
  for (; j < n; ++j)
    a0 += *(const f32x4*)(Hs2 + (size_t)csr[start + j] * FOUT + p * 4);
  f32x4 acc = (a0 + a1) + (a2 + a3);
  float dd = dinv[d];
  f32x4 b = *(const f32x4*)(b2 + p * 4);
  f32x4 z;
  #pragma unroll
  for (int q = 0; q < 4; ++q) z[q] = acc[q] * dd + b[q];

  float m = fmaxf(fmaxf(z[0], z[1]), fmaxf(z[2], z[3]));
  m = fmaxf(m, __shfl_xor(m, 1));
  m = fmaxf(m, __shfl_xor(m, 2));
  float s = expf(z[0]-m) + expf(z[1]-m) + expf(z[2]-m) + expf(z[3]-m);
  s += __shfl_xor(s, 1);
  s += __shfl_xor(s, 2);
  float lse = m + logf(s);
  f32x4 o = { z[0]-lse, z[1]-lse, z[2]-lse, z[3]-lse };
  *(f32x4*)(out + (size_t)d * FOUT + p * 4) = o;
}

extern "C" void kernel_launch(void* const* d_in, const int* in_sizes, int n_in,
                              void* d_out, int out_size, void* d_ws, size_t ws_size,
                              hipStream_t stream) {
  const float* x  = (const float*)d_in[0];
  const float* W1 = (const float*)d_in[1];
  const float* b1 = (const float*)d_in[2];
  const float* W2 = (const float*)d_in[3];
  const float* b2 = (const float*)d_in[4];
  const int*   ei = (const int*)d_in[5];
  const int* srcv = ei;
  const int* dstv = ei + NE;

  char* ws = (char*)d_ws;
  const size_t KB = 1024, MB = 1048576;
  u32*   bcount = (u32*)(ws + 0);           // 784 B
  u32*   bstart = (u32*)(ws + 4 * KB);      // 788 B
  u32*   bcur   = (u32*)(ws + 8 * KB);      // 784 B
  int*   deg    = (int*)(ws + 512 * KB);    // 0.4 MB
  int*   rs     = (int*)(ws + 1024 * KB);   // 0.4 MB
  float* dinv   = (float*)(ws + 1536 * KB); // 0.4 MB
  float* Hs2    = (float*)(ws + 2 * MB);    // 6.4 MB (aliases binned, dead by then)
  u32*   binned = (u32*)(ws + 2 * MB);      // 6.4 MB
  int*   csr    = (int*)(ws + 9 * MB);      // 6.4 MB
  float* Hs1    = (float*)(ws + 16 * MB);   // 12.8 MB
  float* h1     = (float*)(ws + 29 * MB);   // 12.8 MB -> ends 41.8 MB
  float* out    = (float*)d_out;

  hipMemsetAsync(bcount, 0, NBUCK * sizeof(u32), stream);

  k_hist <<<NCHUNK, 256, 0, stream>>>(dstv, bcount);
  k_bscan<<<1,      256, 0, stream>>>(bcount, bstart, bcur);
  k_bin  <<<NCHUNK, 256, 0, stream>>>(srcv, dstv, bcur, binned);
  k_fin  <<<NBUCK,  256, 0, stream>>>(binned, bstart, deg, rs, dinv, csr);
  k_gemm1<<<782, 256, 0, stream>>>(x, W1, dinv, Hs1);
  k_gat1 <<<(NN * 8 + 255) / 256, 256, 0, stream>>>(csr, rs, deg, dinv, b1, Hs1, h1);
  k_gemm2<<<(NN + 255) / 256, 256, 0, stream>>>(h1, W2, dinv, Hs2);
  k_gat2 <<<(NN * 4 + 255) / 256, 256, 0, stream>>>(csr, rs, deg, dinv, b2, Hs2, out);
}

// Round 4
// 166.375 us; speedup vs baseline: 6.7255x; 1.0945x over previous
//
#include <hip/hip_runtime.h>
#include <hip/hip_bf16.h>
#include <cstdint>

#define NN   100000
#define NE   1600000
#define FIN  512
#define FHID 32
#define FOUT 16

#define BSHIFT 9
#define BSIZE  512
#define NBUCK  196                    // ceil(100000/512)
#define EPB    4096                   // edges per chunk block
#define NCHUNK ((NE + EPB - 1) / EPB) // 391

typedef float f32x4 __attribute__((ext_vector_type(4)));
typedef short s16x8 __attribute__((ext_vector_type(8)));
typedef short s16x4 __attribute__((ext_vector_type(4)));
typedef unsigned int u32;
typedef unsigned short u16;

__device__ __forceinline__ short f2bf(float f) {
  union { float f; uint32_t u; } v; v.f = f;
  uint32_t r = v.u + 0x7fffu + ((v.u >> 16) & 1u);
  return (short)(r >> 16);
}
__device__ __forceinline__ float bf2f(u16 u) {
  union { uint32_t u; float f; } v; v.u = (uint32_t)u << 16; return v.f;
}

// ---------------- bucket histogram of dst>>9 --------------------------------
__global__ __launch_bounds__(256) void k_hist(const int* __restrict__ dst,
                                              u32* __restrict__ bcount) {
  __shared__ u32 h[NBUCK];
  int tid = threadIdx.x;
  if (tid < NBUCK) h[tid] = 0;
  __syncthreads();
  int base = blockIdx.x * EPB;
  #pragma unroll
  for (int i = 0; i < EPB / 256; ++i) {
    int e = base + i * 256 + tid;
    if (e < NE) atomicAdd(&h[dst[e] >> BSHIFT], 1u);
  }
  __syncthreads();
  if (tid < NBUCK && h[tid]) atomicAdd(&bcount[tid], h[tid]);
}

// ---------------- scan bucket counts -> bucketStart, init cursors -----------
__global__ __launch_bounds__(256) void k_bscan(const u32* __restrict__ bc,
                                               u32* __restrict__ bstart,
                                               u32* __restrict__ bcur) {
  __shared__ u32 tmp[256];
  int tid = threadIdx.x;
  u32 v = (tid < NBUCK) ? bc[tid] : 0;
  tmp[tid] = v;
  __syncthreads();
  #pragma unroll
  for (int off = 1; off < 256; off <<= 1) {
    u32 t = (tid >= off) ? tmp[tid - off] : 0;
    __syncthreads();
    tmp[tid] += t;
    __syncthreads();
  }
  if (tid < NBUCK) { u32 e = tmp[tid] - v; bstart[tid] = e; bcur[tid] = e; }
  if (tid == 255) bstart[NBUCK] = tmp[255];
}

// ---------------- bin edges by bucket, coalesced writes ---------------------
__global__ __launch_bounds__(256) void k_bin(const int* __restrict__ src,
                                             const int* __restrict__ dst,
                                             u32* __restrict__ bcur,
                                             u32* __restrict__ binned) {
  __shared__ u32 cnt[NBUCK];
  __shared__ u32 lofs[NBUCK];
  __shared__ u32 gbase[NBUCK];
  __shared__ u32 tmp[256];
  __shared__ u32 stage[EPB];
  __shared__ u16 sb[EPB];
  int tid = threadIdx.x;
  if (tid < NBUCK) cnt[tid] = 0;
  __syncthreads();

  int base = blockIdx.x * EPB;
  u32 vals[EPB / 256];
  u32 ofs[EPB / 256];
  int bks[EPB / 256];
  #pragma unroll
  for (int i = 0; i < EPB / 256; ++i) {
    int e = base + i * 256 + tid;
    bool ok = e < NE;
    int s = 0, d = 0;
    if (ok) { s = src[e]; d = dst[e]; }
    int b = ok ? (d >> BSHIFT) : -1;
    bks[i] = b;
    vals[i] = (u32)s | ((u32)(d & (BSIZE - 1)) << 17);
    ofs[i] = ok ? atomicAdd(&cnt[b], 1u) : 0;
  }
  __syncthreads();

  u32 cv = (tid < NBUCK) ? cnt[tid] : 0;
  tmp[tid] = cv;
  __syncthreads();
  #pragma unroll
  for (int off = 1; off < 256; off <<= 1) {
    u32 t = (tid >= off) ? tmp[tid - off] : 0;
    __syncthreads();
    tmp[tid] += t;
    __syncthreads();
  }
  if (tid < NBUCK) {
    lofs[tid] = tmp[tid] - cv;
    gbase[tid] = cv ? atomicAdd(&bcur[tid], cv) : 0;
  }
  __syncthreads();
  u32 total = tmp[255];
  __syncthreads();

  #pragma unroll
  for (int i = 0; i < EPB / 256; ++i) {
    if (bks[i] >= 0) {
      u32 sl = lofs[bks[i]] + ofs[i];
      stage[sl] = vals[i];
      sb[sl] = (u16)bks[i];
    }
  }
  __syncthreads();

  for (u32 s2 = tid; s2 < total; s2 += 256) {
    int b = sb[s2];
    binned[gbase[b] + (s2 - lofs[b])] = stage[s2];
  }
}

// ------- finalize per bucket: deg/dinv/rs + csr (block-local writes) --------
__global__ __launch_bounds__(256) void k_fin(const u32* __restrict__ binned,
                                             const u32* __restrict__ bstart,
                                             int* __restrict__ deg,
                                             int* __restrict__ rs,
                                             float* __restrict__ dinv,
                                             int* __restrict__ csr) {
  __shared__ u32 degl[BSIZE];
  __shared__ u32 rsl[BSIZE];
  __shared__ u32 tmp[256];
  int tid = threadIdx.x;
  int b = blockIdx.x;
  u32 start = bstart[b];
  u32 n = bstart[b + 1] - start;

  degl[tid] = 0; degl[tid + 256] = 0;
  __syncthreads();
  for (u32 k = tid; k < n; k += 256)
    atomicAdd(&degl[binned[start + k] >> 17], 1u);
  __syncthreads();

  u32 a0 = degl[2 * tid], a1 = degl[2 * tid + 1];
  u32 s = a0 + a1;
  tmp[tid] = s;
  __syncthreads();
  #pragma unroll
  for (int off = 1; off < 256; off <<= 1) {
    u32 t = (tid >= off) ? tmp[tid - off] : 0;
    __syncthreads();
    tmp[tid] += t;
    __syncthreads();
  }
  u32 e = tmp[tid] - s;
  rsl[2 * tid] = e;
  rsl[2 * tid + 1] = e + a0;
  __syncthreads();

  #pragma unroll
  for (int q = 0; q < 2; ++q) {
    int t = tid + q * 256;
    int g = b * BSIZE + t;
    if (g < NN) {
      deg[g] = (int)degl[t];
      rs[g] = (int)(start + rsl[t]);
      dinv[g] = rsqrtf(1.0f + (float)degl[t]);
    }
  }
  __syncthreads();

  for (u32 k = tid; k < n; k += 256) {
    u32 v = binned[start + k];
    u32 pos = atomicAdd(&rsl[v >> 17], 1u);
    csr[start + pos] = (int)(v & 0x1FFFFu);
  }
}

// ------- GEMM1: Hs1[N,32](bf16) = (x[N,512] @ W1) * dinv[row] ---------------
__global__ __launch_bounds__(256) void k_gemm1(const float* __restrict__ x,
                                               const float* __restrict__ W1,
                                               const float* __restrict__ dinv,
                                               u16* __restrict__ Hs1) {
  __shared__ s16x8 Blds[16][2][64];
  const int tid = threadIdx.x;
  for (int it = 0; it < 64; ++it) {
    int flat = it * 256 + tid;
    int i  = flat & 7;
    int l  = (flat >> 3) & 63;
    int nt = (flat >> 9) & 1;
    int kt = flat >> 10;
    int k  = kt * 32 + ((l >> 4) << 3) + i;
    int n  = nt * 16 + (l & 15);
    ((short*)Blds)[flat] = f2bf(W1[k * 32 + n]);
  }
  __syncthreads();

  const int lane = tid & 63;
  const int wv   = tid >> 6;
  const int h    = lane >> 4;
  const int m    = lane & 15;
  const int wid  = blockIdx.x * 4 + wv;
  if (wid >= 3125) return;
  const int t0 = wid * 2;

  const float* xr0 = x + (size_t)(t0 * 16 + m) * FIN + h * 8;
  const float* xr1 = xr0 + (size_t)16 * FIN;

  f32x4 acc[2][2] = {};
  #pragma unroll
  for (int kt = 0; kt < 16; ++kt) {
    f32x4 a0 = *(const f32x4*)(xr0 + kt * 32);
    f32x4 a1 = *(const f32x4*)(xr0 + kt * 32 + 4);
    f32x4 c0 = *(const f32x4*)(xr1 + kt * 32);
    f32x4 c1 = *(const f32x4*)(xr1 + kt * 32 + 4);
    s16x8 b0 = Blds[kt][0][lane];
    s16x8 b1 = Blds[kt][1][lane];
    s16x8 af, cf;
    af[0]=f2bf(a0[0]); af[1]=f2bf(a0[1]); af[2]=f2bf(a0[2]); af[3]=f2bf(a0[3]);
    af[4]=f2bf(a1[0]); af[5]=f2bf(a1[1]); af[6]=f2bf(a1[2]); af[7]=f2bf(a1[3]);
    cf[0]=f2bf(c0[0]); cf[1]=f2bf(c0[1]); cf[2]=f2bf(c0[2]); cf[3]=f2bf(c0[3]);
    cf[4]=f2bf(c1[0]); cf[5]=f2bf(c1[1]); cf[6]=f2bf(c1[2]); cf[7]=f2bf(c1[3]);
    acc[0][0] = __builtin_amdgcn_mfma_f32_16x16x32_bf16(af, b0, acc[0][0], 0, 0, 0);
    acc[0][1] = __builtin_amdgcn_mfma_f32_16x16x32_bf16(af, b1, acc[0][1], 0, 0, 0);
    acc[1][0] = __builtin_amdgcn_mfma_f32_16x16x32_bf16(cf, b0, acc[1][0], 0, 0, 0);
    acc[1][1] = __builtin_amdgcn_mfma_f32_16x16x32_bf16(cf, b1, acc[1][1], 0, 0, 0);
  }
  #pragma unroll
  for (int rt = 0; rt < 2; ++rt) {
    #pragma unroll
    for (int r = 0; r < 4; ++r) {
      int row = (t0 + rt) * 16 + h * 4 + r;
      float di = dinv[row];
      u16* o = Hs1 + (size_t)row * FHID + m;
      o[0]  = (u16)f2bf(acc[rt][0][r] * di);
      o[16] = (u16)f2bf(acc[rt][1][r] * di);
    }
  }
}

// ------ gather1 + relu + GEMM2 fused:
//   h1 = relu(dinv[d]*(Σ Hs1[s] + Hs1[d]) + b1);  Hs2 = (h1 @ W2) * dinv[d]
// 4 lanes per node, 8 feats each.
__global__ __launch_bounds__(256) void k_gat1(const int* __restrict__ csr,
                                              const int* __restrict__ rs,
                                              const int* __restrict__ deg,
                                              const float* __restrict__ dinv,
                                              const float* __restrict__ b1,
                                              const float* __restrict__ W2,
                                              const u16* __restrict__ Hs1,
                                              u16* __restrict__ Hs2) {
  __shared__ float w[FHID * FOUT];
  for (int i = threadIdx.x; i < FHID * FOUT; i += 256) w[i] = W2[i];
  __syncthreads();

  int t = blockIdx.x * 256 + threadIdx.x;
  int d = t >> 2;
  if (d >= NN) return;
  int p = t & 3;
  int start = rs[d], n = deg[d];

  float a0[8], a1[8], a2[8], a3[8];
  {
    s16x8 v = *(const s16x8*)(Hs1 + (size_t)d * FHID + p * 8);  // self-loop
    #pragma unroll
    for (int k = 0; k < 8; ++k) {
      a0[k] = bf2f((u16)v[k]); a1[k] = 0.f; a2[k] = 0.f; a3[k] = 0.f;
    }
  }
  int j = 0;
  for (; j + 4 <= n; j += 4) {
    int s0 = csr[start + j];
    int s1 = csr[start + j + 1];
    int s2 = csr[start + j + 2];
    int s3 = csr[start + j + 3];
    s16x8 v0 = *(const s16x8*)(Hs1 + (size_t)s0 * FHID + p * 8);
    s16x8 v1 = *(const s16x8*)(Hs1 + (size_t)s1 * FHID + p * 8);
    s16x8 v2 = *(const s16x8*)(Hs1 + (size_t)s2 * FHID + p * 8);
    s16x8 v3 = *(const s16x8*)(Hs1 + (size_t)s3 * FHID + p * 8);
    #pragma unroll
    for (int k = 0; k < 8; ++k) {
      a0[k] += bf2f((u16)v0[k]);
      a1[k] += bf2f((u16)v1[k]);
      a2[k] += bf2f((u16)v2[k]);
      a3[k] += bf2f((u16)v3[k]);
    }
  }
  for (; j < n; ++j) {
    int s0 = csr[start + j];
    s16x8 v0 = *(const s16x8*)(Hs1 + (size_t)s0 * FHID + p * 8);
    #pragma unroll
    for (int k = 0; k < 8; ++k) a0[k] += bf2f((u16)v0[k]);
  }

  float dd = dinv[d];
  float h[8];
  #pragma unroll
  for (int k = 0; k < 8; ++k)
    h[k] = fmaxf(((a0[k] + a1[k]) + (a2[k] + a3[k])) * dd + b1[p * 8 + k], 0.0f);

  float pj[FOUT];
  #pragma unroll
  for (int jj = 0; jj < FOUT; ++jj) pj[jj] = 0.f;
  #pragma unroll
  for (int k = 0; k < 8; ++k)
    #pragma unroll
    for (int jj = 0; jj < FOUT; ++jj)
      pj[jj] = fmaf(h[k], w[(p * 8 + k) * FOUT + jj], pj[jj]);
  #pragma unroll
  for (int jj = 0; jj < FOUT; ++jj) {
    pj[jj] += __shfl_xor(pj[jj], 1);
    pj[jj] += __shfl_xor(pj[jj], 2);
  }
  s16x4 o;
  #pragma unroll
  for (int q = 0; q < 4; ++q) o[q] = f2bf(pj[p * 4 + q] * dd);
  *(s16x4*)(Hs2 + (size_t)d * FOUT + p * 4) = o;
}

// ------ gather2 + bias + log_softmax.  2 lanes per node, 8 feats each. ------
__global__ __launch_bounds__(256) void k_gat2(const int* __restrict__ csr,
                                              const int* __restrict__ rs,
                                              const int* __restrict__ deg,
                                              const float* __restrict__ dinv,
                                              const float* __restrict__ b2,
                                              const u16* __restrict__ Hs2,
                                              float* __restrict__ out) {
  int t = blockIdx.x * 256 + threadIdx.x;
  int d = t >> 1;
  if (d >= NN) return;
  int p = t & 1;
  int start = rs[d], n = deg[d];

  float a0[8], a1[8], a2[8], a3[8];
  {
    s16x8 v = *(const s16x8*)(Hs2 + (size_t)d * FOUT + p * 8);  // self-loop
    #pragma unroll
    for (int k = 0; k < 8; ++k) {
      a0[k] = bf2f((u16)v[k]); a1[k] = 0.f; a2[k] = 0.f; a3[k] = 0.f;
    }
  }
  int j = 0;
  for (; j + 4 <= n; j += 4) {
    int s0 = csr[start + j];
    int s1 = csr[start + j + 1];
    int s2 = csr[start + j + 2];
    int s3 = csr[start + j + 3];
    s16x8 v0 = *(const s16x8*)(Hs2 + (size_t)s0 * FOUT + p * 8);
    s16x8 v1 = *(const s16x8*)(Hs2 + (size_t)s1 * FOUT + p * 8);
    s16x8 v2 = *(const s16x8*)(Hs2 + (size_t)s2 * FOUT + p * 8);
    s16x8 v3 = *(const s16x8*)(Hs2 + (size_t)s3 * FOUT + p * 8);
    #pragma unroll
    for (int k = 0; k < 8; ++k) {
      a0[k] += bf2f((u16)v0[k]);
      a1[k] += bf2f((u16)v1[k]);
      a2[k] += bf2f((u16)v2[k]);
      a3[k] += bf2f((u16)v3[k]);
    }
  }
  for (; j < n; ++j) {
    int s0 = csr[start + j];
    s16x8 v0 = *(const s16x8*)(Hs2 + (size_t)s0 * FOUT + p * 8);
    #pragma unroll
    for (int k = 0; k < 8; ++k) a0[k] += bf2f((u16)v0[k]);
  }

  float dd = dinv[d];
  float z[8];
  #pragma unroll
  for (int k = 0; k < 8; ++k)
    z[k] = ((a0[k] + a1[k]) + (a2[k] + a3[k])) * dd + b2[p * 8 + k];

  float m = z[0];
  #pragma unroll
  for (int k = 1; k < 8; ++k) m = fmaxf(m, z[k]);
  m = fmaxf(m, __shfl_xor(m, 1));
  float s = 0.f;
  #pragma unroll
  for (int k = 0; k < 8; ++k) s += expf(z[k] - m);
  s += __shfl_xor(s, 1);
  float lse = m + logf(s);

  float* ob = out + (size_t)d * FOUT + p * 8;
  f32x4 o0 = { z[0]-lse, z[1]-lse, z[2]-lse, z[3]-lse };
  f32x4 o1 = { z[4]-lse, z[5]-lse, z[6]-lse, z[7]-lse };
  *(f32x4*)(ob)     = o0;
  *(f32x4*)(ob + 4) = o1;
}

extern "C" void kernel_launch(void* const* d_in, const int* in_sizes, int n_in,
                              void* d_out, int out_size, void* d_ws, size_t ws_size,
                              hipStream_t stream) {
  const float* x  = (const float*)d_in[0];
  const float* W1 = (const float*)d_in[1];
  const float* b1 = (const float*)d_in[2];
  const float* W2 = (const float*)d_in[3];
  const float* b2 = (const float*)d_in[4];
  const int*   ei = (const int*)d_in[5];
  const int* srcv = ei;
  const int* dstv = ei + NE;

  char* ws = (char*)d_ws;
  const size_t KB = 1024, MB = 1048576;
  u32*   bcount = (u32*)(ws + 0);           // 784 B
  u32*   bstart = (u32*)(ws + 4 * KB);      // 788 B
  u32*   bcur   = (u32*)(ws + 8 * KB);      // 784 B
  int*   deg    = (int*)(ws + 512 * KB);    // 0.4 MB
  int*   rs     = (int*)(ws + 1024 * KB);   // 0.4 MB
  float* dinv   = (float*)(ws + 1536 * KB); // 0.4 MB
  u32*   binned = (u32*)(ws + 2 * MB);      // 6.4 MB
  int*   csr    = (int*)(ws + 9 * MB);      // 6.4 MB
  u16*   Hs1    = (u16*)(ws + 16 * MB);     // 6.4 MB (bf16)
  u16*   Hs2    = (u16*)(ws + 23 * MB);     // 3.2 MB (bf16) -> ends ~26.2 MB
  float* out    = (float*)d_out;

  hipMemsetAsync(bcount, 0, NBUCK * sizeof(u32), stream);

  k_hist <<<NCHUNK, 256, 0, stream>>>(dstv, bcount);
  k_bscan<<<1,      256, 0, stream>>>(bcount, bstart, bcur);
  k_bin  <<<NCHUNK, 256, 0, stream>>>(srcv, dstv, bcur, binned);
  k_fin  <<<NBUCK,  256, 0, stream>>>(binned, bstart, deg, rs, dinv, csr);
  k_gemm1<<<782, 256, 0, stream>>>(x, W1, dinv, Hs1);
  k_gat1 <<<(NN * 4 + 255) / 256, 256, 0, stream>>>(csr, rs, deg, dinv, b1, W2, Hs1, Hs2);
  k_gat2 <<<(NN * 2 + 255) / 256, 256, 0, stream>>>(csr, rs, deg, dinv, b2, Hs2, out);
}

// Round 5
// 164.258 us; speedup vs baseline: 6.8122x; 1.0129x over previous
//
#include <hip/hip_runtime.h>
#include <hip/hip_bf16.h>
#include <cstdint>

#define NN   100000
#define NE   1600000
#define FIN  512
#define FHID 32
#define FOUT 16

#define BSHIFT 8
#define BSIZE  256
#define NBUCK  391                    // ceil(100000/256)
#define EPB    2048                   // edges per chunk block
#define NCHUNK ((NE + EPB - 1) / EPB) // 782

typedef float f32x4 __attribute__((ext_vector_type(4)));
typedef short s16x8 __attribute__((ext_vector_type(8)));
typedef short s16x4 __attribute__((ext_vector_type(4)));
typedef int   i32x4 __attribute__((ext_vector_type(4)));
typedef unsigned int u32;
typedef unsigned short u16;

__device__ __forceinline__ short f2bf(float f) {
  union { float f; uint32_t u; } v; v.f = f;
  uint32_t r = v.u + 0x7fffu + ((v.u >> 16) & 1u);
  return (short)(r >> 16);
}
__device__ __forceinline__ float bf2f(u16 u) {
  union { uint32_t u; float f; } v; v.u = (uint32_t)u << 16; return v.f;
}

// ---------------- bucket histogram of dst>>8 --------------------------------
__global__ __launch_bounds__(256) void k_hist(const int* __restrict__ dst,
                                              u32* __restrict__ bcount) {
  __shared__ u32 h[NBUCK];
  int tid = threadIdx.x;
  for (int i = tid; i < NBUCK; i += 256) h[i] = 0;
  __syncthreads();
  int base = blockIdx.x * EPB;
  #pragma unroll
  for (int i = 0; i < 2; ++i) {
    int e0 = base + (i * 256 + tid) * 4;
    if (e0 + 3 < NE) {
      i32x4 d4 = *(const i32x4*)(dst + e0);
      atomicAdd(&h[d4[0] >> BSHIFT], 1u);
      atomicAdd(&h[d4[1] >> BSHIFT], 1u);
      atomicAdd(&h[d4[2] >> BSHIFT], 1u);
      atomicAdd(&h[d4[3] >> BSHIFT], 1u);
    } else {
      for (int k = 0; k < 4; ++k)
        if (e0 + k < NE) atomicAdd(&h[dst[e0 + k] >> BSHIFT], 1u);
    }
  }
  __syncthreads();
  for (int i = tid; i < NBUCK; i += 256)
    if (h[i]) atomicAdd(&bcount[i], h[i]);
}

// ---------------- scan bucket counts -> bucketStart, init cursors -----------
__global__ __launch_bounds__(512) void k_bscan(const u32* __restrict__ bc,
                                               u32* __restrict__ bstart,
                                               u32* __restrict__ bcur) {
  __shared__ u32 tmp[512];
  int tid = threadIdx.x;
  u32 v = (tid < NBUCK) ? bc[tid] : 0;
  tmp[tid] = v;
  __syncthreads();
  #pragma unroll
  for (int off = 1; off < 512; off <<= 1) {
    u32 t = (tid >= off) ? tmp[tid - off] : 0;
    __syncthreads();
    tmp[tid] += t;
    __syncthreads();
  }
  if (tid < NBUCK) { u32 e = tmp[tid] - v; bstart[tid] = e; bcur[tid] = e; }
  if (tid == 511) bstart[NBUCK] = tmp[511];
}

// ---------------- bin edges by bucket, coalesced writes ---------------------
__global__ __launch_bounds__(512) void k_bin(const int* __restrict__ src,
                                             const int* __restrict__ dst,
                                             u32* __restrict__ bcur,
                                             u32* __restrict__ binned) {
  __shared__ u32 cnt[NBUCK];
  __shared__ u32 lofs[NBUCK];
  __shared__ u32 gbase[NBUCK];
  __shared__ u32 tmp[512];
  __shared__ u32 stage[EPB];
  __shared__ u16 sb[EPB];
  int tid = threadIdx.x;
  for (int i = tid; i < NBUCK; i += 512) cnt[i] = 0;
  __syncthreads();

  int base = blockIdx.x * EPB;
  int e0 = base + tid * 4;
  u32 vals[4];
  u32 ofs[4];
  int bks[4];
  if (e0 + 3 < NE) {
    i32x4 s4 = *(const i32x4*)(src + e0);
    i32x4 d4 = *(const i32x4*)(dst + e0);
    #pragma unroll
    for (int k = 0; k < 4; ++k) {
      int b = d4[k] >> BSHIFT;
      bks[k] = b;
      vals[k] = (u32)s4[k] | ((u32)(d4[k] & (BSIZE - 1)) << 17);
      ofs[k] = atomicAdd(&cnt[b], 1u);
    }
  } else {
    #pragma unroll
    for (int k = 0; k < 4; ++k) {
      int e = e0 + k;
      bool ok = e < NE;
      int s = 0, d = 0;
      if (ok) { s = src[e]; d = dst[e]; }
      int b = ok ? (d >> BSHIFT) : -1;
      bks[k] = b;
      vals[k] = (u32)s | ((u32)(d & (BSIZE - 1)) << 17);
      ofs[k] = ok ? atomicAdd(&cnt[b], 1u) : 0;
    }
  }
  __syncthreads();

  u32 cv = (tid < NBUCK) ? cnt[tid] : 0;
  tmp[tid] = cv;
  __syncthreads();
  #pragma unroll
  for (int off = 1; off < 512; off <<= 1) {
    u32 t = (tid >= off) ? tmp[tid - off] : 0;
    __syncthreads();
    tmp[tid] += t;
    __syncthreads();
  }
  if (tid < NBUCK) {
    lofs[tid] = tmp[tid] - cv;
    gbase[tid] = cv ? atomicAdd(&bcur[tid], cv) : 0;
  }
  __syncthreads();
  u32 total = tmp[511];
  __syncthreads();

  #pragma unroll
  for (int k = 0; k < 4; ++k) {
    if (bks[k] >= 0) {
      u32 sl = lofs[bks[k]] + ofs[k];
      stage[sl] = vals[k];
      sb[sl] = (u16)bks[k];
    }
  }
  __syncthreads();

  for (u32 s2 = tid; s2 < total; s2 += 512) {
    int b = sb[s2];
    binned[gbase[b] + (s2 - lofs[b])] = stage[s2];
  }
}

// ------- finalize per bucket: deg/dinv/rs + csr (block-local writes) --------
__global__ __launch_bounds__(256) void k_fin(const u32* __restrict__ binned,
                                             const u32* __restrict__ bstart,
                                             int* __restrict__ deg,
                                             int* __restrict__ rs,
                                             float* __restrict__ dinv,
                                             int* __restrict__ csr) {
  __shared__ u32 degl[BSIZE];
  __shared__ u32 rsl[BSIZE];
  int tid = threadIdx.x;
  int b = blockIdx.x;
  u32 start = bstart[b];
  u32 n = bstart[b + 1] - start;

  degl[tid] = 0;
  __syncthreads();
  for (u32 k = tid; k < n; k += 256)
    atomicAdd(&degl[binned[start + k] >> 17], 1u);
  __syncthreads();

  // exclusive scan of degl[256]
  u32 v = degl[tid];
  rsl[tid] = v;
  __syncthreads();
  #pragma unroll
  for (int off = 1; off < 256; off <<= 1) {
    u32 t = (tid >= off) ? rsl[tid - off] : 0;
    __syncthreads();
    rsl[tid] += t;
    __syncthreads();
  }
  u32 e = rsl[tid] - v;   // exclusive
  __syncthreads();
  rsl[tid] = e;

  int g = b * BSIZE + tid;
  if (g < NN) {
    deg[g] = (int)v;
    rs[g] = (int)(start + e);
    dinv[g] = rsqrtf(1.0f + (float)v);
  }
  __syncthreads();

  for (u32 k = tid; k < n; k += 256) {
    u32 vv = binned[start + k];
    u32 pos = atomicAdd(&rsl[vv >> 17], 1u);
    csr[start + pos] = (int)(vv & 0x1FFFFu);
  }
}

// ------- GEMM1: Hs1[N,32](bf16) = (x[N,512] @ W1) * dinv[row] ---------------
__global__ __launch_bounds__(256) void k_gemm1(const float* __restrict__ x,
                                               const float* __restrict__ W1,
                                               const float* __restrict__ dinv,
                                               u16* __restrict__ Hs1) {
  __shared__ s16x8 Blds[16][2][64];
  const int tid = threadIdx.x;
  for (int it = 0; it < 64; ++it) {
    int flat = it * 256 + tid;
    int i  = flat & 7;
    int l  = (flat >> 3) & 63;
    int nt = (flat >> 9) & 1;
    int kt = flat >> 10;
    int k  = kt * 32 + ((l >> 4) << 3) + i;
    int n  = nt * 16 + (l & 15);
    ((short*)Blds)[flat] = f2bf(W1[k * 32 + n]);
  }
  __syncthreads();

  const int lane = tid & 63;
  const int wv   = tid >> 6;
  const int h    = lane >> 4;
  const int m    = lane & 15;
  const int wid  = blockIdx.x * 4 + wv;
  if (wid >= 3125) return;
  const int t0 = wid * 2;

  const float* xr0 = x + (size_t)(t0 * 16 + m) * FIN + h * 8;
  const float* xr1 = xr0 + (size_t)16 * FIN;

  f32x4 acc[2][2] = {};
  #pragma unroll
  for (int kt = 0; kt < 16; ++kt) {
    f32x4 a0 = *(const f32x4*)(xr0 + kt * 32);
    f32x4 a1 = *(const f32x4*)(xr0 + kt * 32 + 4);
    f32x4 c0 = *(const f32x4*)(xr1 + kt * 32);
    f32x4 c1 = *(const f32x4*)(xr1 + kt * 32 + 4);
    s16x8 b0 = Blds[kt][0][lane];
    s16x8 b1 = Blds[kt][1][lane];
    s16x8 af, cf;
    af[0]=f2bf(a0[0]); af[1]=f2bf(a0[1]); af[2]=f2bf(a0[2]); af[3]=f2bf(a0[3]);
    af[4]=f2bf(a1[0]); af[5]=f2bf(a1[1]); af[6]=f2bf(a1[2]); af[7]=f2bf(a1[3]);
    cf[0]=f2bf(c0[0]); cf[1]=f2bf(c0[1]); cf[2]=f2bf(c0[2]); cf[3]=f2bf(c0[3]);
    cf[4]=f2bf(c1[0]); cf[5]=f2bf(c1[1]); cf[6]=f2bf(c1[2]); cf[7]=f2bf(c1[3]);
    acc[0][0] = __builtin_amdgcn_mfma_f32_16x16x32_bf16(af, b0, acc[0][0], 0, 0, 0);
    acc[0][1] = __builtin_amdgcn_mfma_f32_16x16x32_bf16(af, b1, acc[0][1], 0, 0, 0);
    acc[1][0] = __builtin_amdgcn_mfma_f32_16x16x32_bf16(cf, b0, acc[1][0], 0, 0, 0);
    acc[1][1] = __builtin_amdgcn_mfma_f32_16x16x32_bf16(cf, b1, acc[1][1], 0, 0, 0);
  }
  #pragma unroll
  for (int rt = 0; rt < 2; ++rt) {
    #pragma unroll
    for (int r = 0; r < 4; ++r) {
      int row = (t0 + rt) * 16 + h * 4 + r;
      float di = dinv[row];
      u16* o = Hs1 + (size_t)row * FHID + m;
      o[0]  = (u16)f2bf(acc[rt][0][r] * di);
      o[16] = (u16)f2bf(acc[rt][1][r] * di);
    }
  }
}

// ------ gather1 + relu + GEMM2 fused (4 lanes/node, 8 feats, ILP-8) ---------
__global__ __launch_bounds__(256) void k_gat1(const int* __restrict__ csr,
                                              const int* __restrict__ rs,
                                              const int* __restrict__ deg,
                                              const float* __restrict__ dinv,
                                              const float* __restrict__ b1,
                                              const float* __restrict__ W2,
                                              const u16* __restrict__ Hs1,
                                              u16* __restrict__ Hs2) {
  __shared__ float w[FHID * FOUT];
  for (int i = threadIdx.x; i < FHID * FOUT; i += 256) w[i] = W2[i];
  __syncthreads();

  int t = blockIdx.x * 256 + threadIdx.x;
  int d = t >> 2;
  if (d >= NN) return;
  int p = t & 3;
  int start = rs[d], n = deg[d];

  float a0[8], a1[8], a2[8], a3[8];
  {
    s16x8 v = *(const s16x8*)(Hs1 + (size_t)d * FHID + p * 8);  // self-loop
    #pragma unroll
    for (int k = 0; k < 8; ++k) {
      a0[k] = bf2f((u16)v[k]); a1[k] = 0.f; a2[k] = 0.f; a3[k] = 0.f;
    }
  }
  int j = 0;
  for (; j + 8 <= n; j += 8) {
    int s0 = csr[start + j];
    int s1 = csr[start + j + 1];
    int s2 = csr[start + j + 2];
    int s3 = csr[start + j + 3];
    int s4 = csr[start + j + 4];
    int s5 = csr[start + j + 5];
    int s6 = csr[start + j + 6];
    int s7 = csr[start + j + 7];
    s16x8 v0 = *(const s16x8*)(Hs1 + (size_t)s0 * FHID + p * 8);
    s16x8 v1 = *(const s16x8*)(Hs1 + (size_t)s1 * FHID + p * 8);
    s16x8 v2 = *(const s16x8*)(Hs1 + (size_t)s2 * FHID + p * 8);
    s16x8 v3 = *(const s16x8*)(Hs1 + (size_t)s3 * FHID + p * 8);
    s16x8 v4 = *(const s16x8*)(Hs1 + (size_t)s4 * FHID + p * 8);
    s16x8 v5 = *(const s16x8*)(Hs1 + (size_t)s5 * FHID + p * 8);
    s16x8 v6 = *(const s16x8*)(Hs1 + (size_t)s6 * FHID + p * 8);
    s16x8 v7 = *(const s16x8*)(Hs1 + (size_t)s7 * FHID + p * 8);
    #pragma unroll
    for (int k = 0; k < 8; ++k) {
      a0[k] += bf2f((u16)v0[k]);
      a1[k] += bf2f((u16)v1[k]);
      a2[k] += bf2f((u16)v2[k]);
      a3[k] += bf2f((u16)v3[k]);
      a0[k] += bf2f((u16)v4[k]);
      a1[k] += bf2f((u16)v5[k]);
      a2[k] += bf2f((u16)v6[k]);
      a3[k] += bf2f((u16)v7[k]);
    }
  }
  for (; j + 4 <= n; j += 4) {
    int s0 = csr[start + j];
    int s1 = csr[start + j + 1];
    int s2 = csr[start + j + 2];
    int s3 = csr[start + j + 3];
    s16x8 v0 = *(const s16x8*)(Hs1 + (size_t)s0 * FHID + p * 8);
    s16x8 v1 = *(const s16x8*)(Hs1 + (size_t)s1 * FHID + p * 8);
    s16x8 v2 = *(const s16x8*)(Hs1 + (size_t)s2 * FHID + p * 8);
    s16x8 v3 = *(const s16x8*)(Hs1 + (size_t)s3 * FHID + p * 8);
    #pragma unroll
    for (int k = 0; k < 8; ++k) {
      a0[k] += bf2f((u16)v0[k]);
      a1[k] += bf2f((u16)v1[k]);
      a2[k] += bf2f((u16)v2[k]);
      a3[k] += bf2f((u16)v3[k]);
    }
  }
  for (; j < n; ++j) {
    int s0 = csr[start + j];
    s16x8 v0 = *(const s16x8*)(Hs1 + (size_t)s0 * FHID + p * 8);
    #pragma unroll
    for (int k = 0; k < 8; ++k) a0[k] += bf2f((u16)v0[k]);
  }

  float dd = dinv[d];
  float h[8];
  #pragma unroll
  for (int k = 0; k < 8; ++k)
    h[k] = fmaxf(((a0[k] + a1[k]) + (a2[k] + a3[k])) * dd + b1[p * 8 + k], 0.0f);

  float pj[FOUT];
  #pragma unroll
  for (int jj = 0; jj < FOUT; ++jj) pj[jj] = 0.f;
  #pragma unroll
  for (int k = 0; k < 8; ++k)
    #pragma unroll
    for (int jj = 0; jj < FOUT; ++jj)
      pj[jj] = fmaf(h[k], w[(p * 8 + k) * FOUT + jj], pj[jj]);
  #pragma unroll
  for (int jj = 0; jj < FOUT; ++jj) {
    pj[jj] += __shfl_xor(pj[jj], 1);
    pj[jj] += __shfl_xor(pj[jj], 2);
  }
  s16x4 o;
  #pragma unroll
  for (int q = 0; q < 4; ++q) o[q] = f2bf(pj[p * 4 + q] * dd);
  *(s16x4*)(Hs2 + (size_t)d * FOUT + p * 4) = o;
}

// ------ gather2 + bias + log_softmax (4 lanes/node, 4 feats, ILP-8) ---------
__global__ __launch_bounds__(256) void k_gat2(const int* __restrict__ csr,
                                              const int* __restrict__ rs,
                                              const int* __restrict__ deg,
                                              const float* __restrict__ dinv,
                                              const float* __restrict__ b2,
                                              const u16* __restrict__ Hs2,
                                              float* __restrict__ out) {
  int t = blockIdx.x * 256 + threadIdx.x;
  int d = t >> 2;
  if (d >= NN) return;
  int p = t & 3;
  int start = rs[d], n = deg[d];

  float a0[4], a1[4], a2[4], a3[4];
  {
    s16x4 v = *(const s16x4*)(Hs2 + (size_t)d * FOUT + p * 4);  // self-loop
    #pragma unroll
    for (int k = 0; k < 4; ++k) {
      a0[k] = bf2f((u16)v[k]); a1[k] = 0.f; a2[k] = 0.f; a3[k] = 0.f;
    }
  }
  int j = 0;
  for (; j + 8 <= n; j += 8) {
    int s0 = csr[start + j];
    int s1 = csr[start + j + 1];
    int s2 = csr[start + j + 2];
    int s3 = csr[start + j + 3];
    int s4 = csr[start + j + 4];
    int s5 = csr[start + j + 5];
    int s6 = csr[start + j + 6];
    int s7 = csr[start + j + 7];
    s16x4 v0 = *(const s16x4*)(Hs2 + (size_t)s0 * FOUT + p * 4);
    s16x4 v1 = *(const s16x4*)(Hs2 + (size_t)s1 * FOUT + p * 4);
    s16x4 v2 = *(const s16x4*)(Hs2 + (size_t)s2 * FOUT + p * 4);
    s16x4 v3 = *(const s16x4*)(Hs2 + (size_t)s3 * FOUT + p * 4);
    s16x4 v4 = *(const s16x4*)(Hs2 + (size_t)s4 * FOUT + p * 4);
    s16x4 v5 = *(const s16x4*)(Hs2 + (size_t)s5 * FOUT + p * 4);
    s16x4 v6 = *(const s16x4*)(Hs2 + (size_t)s6 * FOUT + p * 4);
    s16x4 v7 = *(const s16x4*)(Hs2 + (size_t)s7 * FOUT + p * 4);
    #pragma unroll
    for (int k = 0; k < 4; ++k) {
      a0[k] += bf2f((u16)v0[k]);
      a1[k] += bf2f((u16)v1[k]);
      a2[k] += bf2f((u16)v2[k]);
      a3[k] += bf2f((u16)v3[k]);
      a0[k] += bf2f((u16)v4[k]);
      a1[k] += bf2f((u16)v5[k]);
      a2[k] += bf2f((u16)v6[k]);
      a3[k] += bf2f((u16)v7[k]);
    }
  }
  for (; j + 4 <= n; j += 4) {
    int s0 = csr[start + j];
    int s1 = csr[start + j + 1];
    int s2 = csr[start + j + 2];
    int s3 = csr[start + j + 3];
    s16x4 v0 = *(const s16x4*)(Hs2 + (size_t)s0 * FOUT + p * 4);
    s16x4 v1 = *(const s16x4*)(Hs2 + (size_t)s1 * FOUT + p * 4);
    s16x4 v2 = *(const s16x4*)(Hs2 + (size_t)s2 * FOUT + p * 4);
    s16x4 v3 = *(const s16x4*)(Hs2 + (size_t)s3 * FOUT + p * 4);
    #pragma unroll
    for (int k = 0; k < 4; ++k) {
      a0[k] += bf2f((u16)v0[k]);
      a1[k] += bf2f((u16)v1[k]);
      a2[k] += bf2f((u16)v2[k]);
      a3[k] += bf2f((u16)v3[k]);
    }
  }
  for (; j < n; ++j) {
    int s0 = csr[start + j];
    s16x4 v0 = *(const s16x4*)(Hs2 + (size_t)s0 * FOUT + p * 4);
    #pragma unroll
    for (int k = 0; k < 4; ++k) a0[k] += bf2f((u16)v0[k]);
  }

  float dd = dinv[d];
  float z[4];
  #pragma unroll
  for (int k = 0; k < 4; ++k)
    z[k] = ((a0[k] + a1[k]) + (a2[k] + a3[k])) * dd + b2[p * 4 + k];

  float m = fmaxf(fmaxf(z[0], z[1]), fmaxf(z[2], z[3]));
  m = fmaxf(m, __shfl_xor(m, 1));
  m = fmaxf(m, __shfl_xor(m, 2));
  float s = expf(z[0]-m) + expf(z[1]-m) + expf(z[2]-m) + expf(z[3]-m);
  s += __shfl_xor(s, 1);
  s += __shfl_xor(s, 2);
  float lse = m + logf(s);

  f32x4 o = { z[0]-lse, z[1]-lse, z[2]-lse, z[3]-lse };
  *(f32x4*)(out + (size_t)d * FOUT + p * 4) = o;
}

extern "C" void kernel_launch(void* const* d_in, const int* in_sizes, int n_in,
                              void* d_out, int out_size, void* d_ws, size_t ws_size,
                              hipStream_t stream) {
  const float* x  = (const float*)d_in[0];
  const float* W1 = (const float*)d_in[1];
  const float* b1 = (const float*)d_in[2];
  const float* W2 = (const float*)d_in[3];
  const float* b2 = (const float*)d_in[4];
  const int*   ei = (const int*)d_in[5];
  const int* srcv = ei;
  const int* dstv = ei + NE;

  char* ws = (char*)d_ws;
  const size_t KB = 1024, MB = 1048576;
  u32*   bcount = (u32*)(ws + 0);           // 1.6 KB
  u32*   bstart = (u32*)(ws + 8 * KB);      // 1.6 KB
  u32*   bcur   = (u32*)(ws + 16 * KB);     // 1.6 KB
  int*   deg    = (int*)(ws + 512 * KB);    // 0.4 MB
  int*   rs     = (int*)(ws + 1024 * KB);   // 0.4 MB
  float* dinv   = (float*)(ws + 1536 * KB); // 0.4 MB
  u32*   binned = (u32*)(ws + 2 * MB);      // 6.4 MB
  int*   csr    = (int*)(ws + 9 * MB);      // 6.4 MB
  u16*   Hs1    = (u16*)(ws + 16 * MB);     // 6.4 MB (bf16)
  u16*   Hs2    = (u16*)(ws + 23 * MB);     // 3.2 MB (bf16) -> ends ~26.2 MB
  float* out    = (float*)d_out;

  hipMemsetAsync(bcount, 0, NBUCK * sizeof(u32), stream);

  k_hist <<<NCHUNK, 256, 0, stream>>>(dstv, bcount);
  k_bscan<<<1,      512, 0, stream>>>(bcount, bstart, bcur);
  k_bin  <<<NCHUNK, 512, 0, stream>>>(srcv, dstv, bcur, binned);
  k_fin  <<<NBUCK,  256, 0, stream>>>(binned, bstart, deg, rs, dinv, csr);
  k_gemm1<<<782, 256, 0, stream>>>(x, W1, dinv, Hs1);
  k_gat1 <<<(NN * 4 + 255) / 256, 256, 0, stream>>>(csr, rs, deg, dinv, b1, W2, Hs1, Hs2);
  k_gat2 <<<(NN * 4 + 255) / 256, 256, 0, stream>>>(csr, rs, deg, dinv, b2, Hs2, out);
}